// Round 5
// baseline (940.853 us; speedup 1.0000x reference)
//
#include <hip/hip_runtime.h>
#include <hip/hip_bf16.h>
#include <math.h>

#define BB 2
#define LL 1024
#define EE 512
#define HH 8
#define DD 64
#define NROWS (BB*LL)   // 2048
#define QT 8
#define KSPLIT 8
#define KRANGE (LL/KSPLIT)  // 128

typedef __attribute__((ext_vector_type(4))) float f32x4;
typedef __attribute__((ext_vector_type(2))) float f32x2;
typedef __attribute__((ext_vector_type(8))) short short8;

static __device__ __forceinline__ short to_bf16(float f) {
    __bf16 h = (__bf16)f;
    return __builtin_bit_cast(short, h);
}

static __device__ __forceinline__ float from_bf16(short s) {
    unsigned u = ((unsigned)(unsigned short)s) << 16;
    return __builtin_bit_cast(float, u);
}

static __device__ __forceinline__ float fast_silu(float x) {
    float e = __expf(-x);
    return x * __builtin_amdgcn_rcpf(1.f + e);
}

// -------- shared MFMA GEMM core: acc += X[64-tile] @ W[64-tile]^T (bf16) --------
__device__ __forceinline__ void gemm_core(const float* __restrict__ X,
                                          const float* __restrict__ W,
                                          short* As, short* Bs,
                                          int m0, int n0, f32x4 (&acc)[2][2])
{
    const int tid  = threadIdx.x;
    const int lane = tid & 63, wave = tid >> 6;
    const int wr = wave >> 1, wc = wave & 1;
    const int r = tid >> 2, cq = tid & 3;
    const float* ax = X + (size_t)(m0 + r) * EE + cq * 8;
    const float* bx = W + (size_t)(n0 + r) * EE + cq * 8;

    float a_reg[8], b_reg[8];
    #pragma unroll
    for (int j = 0; j < 8; ++j) { a_reg[j] = ax[j]; b_reg[j] = bx[j]; }

    short* apos = &As[r * 32 + ((cq ^ (r & 3)) * 8)];
    short* bpos = &Bs[r * 32 + ((cq ^ (r & 3)) * 8)];
    const int swz = ((lane >> 4) ^ (lane & 3)) * 8;

    for (int it = 0; it < 16; ++it) {
        short8 av, bv;
        #pragma unroll
        for (int j = 0; j < 8; ++j) { av[j] = to_bf16(a_reg[j]); bv[j] = to_bf16(b_reg[j]); }
        __syncthreads();
        *reinterpret_cast<short8*>(apos) = av;
        *reinterpret_cast<short8*>(bpos) = bv;
        __syncthreads();
        if (it < 15) {
            const float* axn = ax + (it + 1) * 32;
            const float* bxn = bx + (it + 1) * 32;
            #pragma unroll
            for (int j = 0; j < 8; ++j) { a_reg[j] = axn[j]; b_reg[j] = bxn[j]; }
        }
        short8 af[2], bf[2];
        #pragma unroll
        for (int mi = 0; mi < 2; ++mi) {
            int row = wr * 32 + mi * 16 + (lane & 15);
            af[mi] = *reinterpret_cast<short8*>(&As[row * 32 + swz]);
        }
        #pragma unroll
        for (int ni = 0; ni < 2; ++ni) {
            int row = wc * 32 + ni * 16 + (lane & 15);
            bf[ni] = *reinterpret_cast<short8*>(&Bs[row * 32 + swz]);
        }
        #pragma unroll
        for (int mi = 0; mi < 2; ++mi)
            #pragma unroll
            for (int ni = 0; ni < 2; ++ni)
                acc[mi][ni] = __builtin_amdgcn_mfma_f32_16x16x32_bf16(af[mi], bf[ni], acc[mi][ni], 0, 0, 0);
    }
}

// -------- fused Q/K/V projections; z=0:Q(bf16) z=1:K(bf16) z=2:V(f32) --------
__global__ __launch_bounds__(256) void qkv_gemm(const float* __restrict__ q_in,
                                                const float* __restrict__ k_in,
                                                const float* __restrict__ v_in,
                                                const float* __restrict__ Wq,
                                                const float* __restrict__ Wk,
                                                const float* __restrict__ Wv,
                                                const float* __restrict__ bq,
                                                const float* __restrict__ bk,
                                                const float* __restrict__ bv,
                                                short* __restrict__ Qo,
                                                short* __restrict__ Ko,
                                                float* __restrict__ Vo)
{
    __shared__ short As[64 * 32];
    __shared__ short Bs[64 * 32];
    const int z = blockIdx.z;
    const float* X = (z == 0) ? q_in : (z == 1) ? k_in : v_in;
    const float* W = (z == 0) ? Wq : (z == 1) ? Wk : Wv;
    const float* bias = (z == 0) ? bq : (z == 1) ? bk : bv;

    const int m0 = blockIdx.x * 64, n0 = blockIdx.y * 64;
    f32x4 acc[2][2];
    #pragma unroll
    for (int mi = 0; mi < 2; ++mi)
        #pragma unroll
        for (int ni = 0; ni < 2; ++ni) acc[mi][ni] = (f32x4){0.f,0.f,0.f,0.f};

    gemm_core(X, W, As, Bs, m0, n0, acc);

    const int tid = threadIdx.x, lane = tid & 63, wave = tid >> 6;
    const int wr = wave >> 1, wc = wave & 1;
    const int col_l = lane & 15, rowg = (lane >> 4) * 4;
    #pragma unroll
    for (int mi = 0; mi < 2; ++mi)
        #pragma unroll
        for (int ni = 0; ni < 2; ++ni) {
            int colg = n0 + wc * 32 + ni * 16 + col_l;
            float bn = bias[colg];
            #pragma unroll
            for (int rr = 0; rr < 4; ++rr) {
                int mg = m0 + wr * 32 + mi * 16 + rowg + rr;
                float v = acc[mi][ni][rr] + bn;
                if (z == 2) Vo[(size_t)mg * EE + colg] = v;
                else {
                    short* ob = z ? Ko : Qo;
                    ob[(size_t)mg * EE + colg] = to_bf16(v);
                }
            }
        }
}

// -------- output GEMM: X = sum of 8 bf16 partial arrays --------
__global__ __launch_bounds__(256) void gemmO(const short* __restrict__ P,   // [KSPLIT][2048][512] bf16
                                             const float* __restrict__ W,
                                             const float* __restrict__ bias,
                                             float* __restrict__ out)
{
    __shared__ short As[64 * 32];
    __shared__ short Bs[64 * 32];
    const int tid  = threadIdx.x;
    const int lane = tid & 63, wave = tid >> 6;
    const int wr = wave >> 1, wc = wave & 1;
    const int m0 = blockIdx.x * 64, n0 = blockIdx.y * 64;
    const int r = tid >> 2, cq = tid & 3;
    const size_t PSZ = (size_t)NROWS * EE;

    size_t xoff = (size_t)(m0 + r) * EE + cq * 8;
    const float* bx = W + (size_t)(n0 + r) * EE + cq * 8;

    float a_reg[8], b_reg[8];
    #pragma unroll
    for (int j = 0; j < 8; ++j) { a_reg[j] = 0.f; b_reg[j] = bx[j]; }
    #pragma unroll
    for (int p = 0; p < KSPLIT; ++p) {
        short8 v = *reinterpret_cast<const short8*>(&P[p * PSZ + xoff]);
        #pragma unroll
        for (int j = 0; j < 8; ++j) a_reg[j] += from_bf16(v[j]);
    }

    f32x4 acc[2][2];
    #pragma unroll
    for (int mi = 0; mi < 2; ++mi)
        #pragma unroll
        for (int ni = 0; ni < 2; ++ni) acc[mi][ni] = (f32x4){0.f,0.f,0.f,0.f};

    short* apos = &As[r * 32 + ((cq ^ (r & 3)) * 8)];
    short* bpos = &Bs[r * 32 + ((cq ^ (r & 3)) * 8)];
    const int swz = ((lane >> 4) ^ (lane & 3)) * 8;

    for (int it = 0; it < 16; ++it) {
        short8 av, bv;
        #pragma unroll
        for (int j = 0; j < 8; ++j) { av[j] = to_bf16(a_reg[j]); bv[j] = to_bf16(b_reg[j]); }
        __syncthreads();
        *reinterpret_cast<short8*>(apos) = av;
        *reinterpret_cast<short8*>(bpos) = bv;
        __syncthreads();
        if (it < 15) {
            size_t xo = xoff + (it + 1) * 32;
            const float* bxn = bx + (it + 1) * 32;
            #pragma unroll
            for (int j = 0; j < 8; ++j) { a_reg[j] = 0.f; b_reg[j] = bxn[j]; }
            #pragma unroll
            for (int p = 0; p < KSPLIT; ++p) {
                short8 v = *reinterpret_cast<const short8*>(&P[p * PSZ + xo]);
                #pragma unroll
                for (int j = 0; j < 8; ++j) a_reg[j] += from_bf16(v[j]);
            }
        }
        short8 af[2], bf[2];
        #pragma unroll
        for (int mi = 0; mi < 2; ++mi) {
            int row = wr * 32 + mi * 16 + (lane & 15);
            af[mi] = *reinterpret_cast<short8*>(&As[row * 32 + swz]);
        }
        #pragma unroll
        for (int ni = 0; ni < 2; ++ni) {
            int row = wc * 32 + ni * 16 + (lane & 15);
            bf[ni] = *reinterpret_cast<short8*>(&Bs[row * 32 + swz]);
        }
        #pragma unroll
        for (int mi = 0; mi < 2; ++mi)
            #pragma unroll
            for (int ni = 0; ni < 2; ++ni)
                acc[mi][ni] = __builtin_amdgcn_mfma_f32_16x16x32_bf16(af[mi], bf[ni], acc[mi][ni], 0, 0, 0);
    }

    const int col_l = lane & 15, rowg = (lane >> 4) * 4;
    #pragma unroll
    for (int mi = 0; mi < 2; ++mi)
        #pragma unroll
        for (int ni = 0; ni < 2; ++ni) {
            int colg = n0 + wc * 32 + ni * 16 + col_l;
            float bn = bias[colg];
            #pragma unroll
            for (int rr = 0; rr < 4; ++rr) {
                int mg = m0 + wr * 32 + mi * 16 + rowg + rr;
                out[(size_t)mg * EE + colg] = acc[mi][ni][rr] + bn;
            }
        }
}

// -------- fused attention --------
// Qb,Kb: bf16 [B*L][E]; V: f32 [B*L][E]; ATTp: bf16 [KSPLIT][B*L][E] partials.
// sw layout: [k(64)][h*8 + q], row stride 68 floats.
__global__ __launch_bounds__(256, 6) void attn5(const short* __restrict__ Qb,
                                                const short* __restrict__ Kb,
                                                const float* __restrict__ V,
                                                short* __restrict__ ATTp)
{
    __shared__ float sw[64 * 68];     // 17.4 KB (only LDS)

    const int tid = threadIdx.x, lane = tid & 63, wave = tid >> 6;

    // XCD-aware decode over 2048 blocks: each XCD chunk owns one (b, k-eighth pair)
    const int fid = blockIdx.x;                    // 0..2047
    const int newid = (fid & 7) * 256 + (fid >> 3);
    const int b = newid >> 10;
    const int ksp = (newid >> 7) & 7;
    const int qpos = newid & 127;
    const int bq0 = b * LL + qpos * QT;
    const int k0base = ksp * KRANGE;

    f32x2 oacc[4][HH];
    #pragma unroll
    for (int qp = 0; qp < 4; ++qp)
        #pragma unroll
        for (int h = 0; h < HH; ++h) oacc[qp][h] = (f32x2){0.f, 0.f};

    const int qr = lane & 7;
    const int kg4 = lane >> 4;

    for (int t = 0; t < KRANGE / 64; ++t) {
        const int k0 = k0base + t * 64;
        __syncthreads();   // sw free (prev phase 3 done)

        // ---- phase 1: MFMA scores S^T[k][q] for heads {wave, wave+4} ----
        const short* kbase = Kb + ((size_t)(b * LL + k0) << 9);
        const short* qrow = Qb + ((size_t)(bq0 + qr) << 9);
        #pragma unroll
        for (int hh = 0; hh < 2; ++hh) {
            const int h = wave + hh * 4;
            short8 bfq[2];
            #pragma unroll
            for (int kc = 0; kc < 2; ++kc)
                bfq[kc] = *reinterpret_cast<const short8*>(qrow + ((h * 8 + kc * 4 + kg4) << 3));
            f32x4 acc[4];
            #pragma unroll
            for (int m = 0; m < 4; ++m) acc[m] = (f32x4){0.f,0.f,0.f,0.f};
            #pragma unroll
            for (int m = 0; m < 4; ++m) {
                const short* arow = kbase + ((size_t)(m * 16 + (lane & 15)) << 9) + (h << 6) + (kg4 << 3);
                short8 af0 = *reinterpret_cast<const short8*>(arow);
                short8 af1 = *reinterpret_cast<const short8*>(arow + 32);
                acc[m] = __builtin_amdgcn_mfma_f32_16x16x32_bf16(af0, bfq[0], acc[m], 0, 0, 0);
                acc[m] = __builtin_amdgcn_mfma_f32_16x16x32_bf16(af1, bfq[1], acc[m], 0, 0, 0);
            }
            if ((lane & 15) < 8) {
                int q = lane & 15;
                #pragma unroll
                for (int m = 0; m < 4; ++m)
                    #pragma unroll
                    for (int r = 0; r < 4; ++r) {
                        int k = m * 16 + kg4 * 4 + r;
                        sw[k * 68 + h * 8 + q] = acc[m][r] * 0.125f;
                    }
            }
        }
        __syncthreads();

        // ---- phase 2: RMS over heads, normalize in place ----
        #pragma unroll
        for (int rep = 0; rep < 2; ++rep) {
            int idx = rep * 256 + tid;
            int k = idx >> 3, q = idx & 7;
            float* sp = &sw[k * 68 + q];
            float s[HH], ss = 0.f;
            #pragma unroll
            for (int h = 0; h < HH; ++h) { s[h] = sp[h * 8]; ss += s[h] * s[h]; }
            float inv = __builtin_amdgcn_rsqf(ss * 0.125f + 1e-8f);
            #pragma unroll
            for (int h = 0; h < HH; ++h) sp[h * 8] = s[h] * inv;
        }
        __syncthreads();

        // ---- phase 3: rolled loop; lane = d, k = j*4+wave ----
        for (int j = 0; j < 16; ++j) {
            int kl = j * 4 + wave;
            const float* vp = V + ((size_t)(b * LL + k0 + kl) << 9) + lane;
            float vr[HH];
            #pragma unroll
            for (int h = 0; h < HH; ++h) vr[h] = vp[h * DD];
            const float* swr = &sw[kl * 68];
            f32x2 xv[4];
            #pragma unroll
            for (int qp = 0; qp < 4; ++qp) xv[qp] = (f32x2){0.f, 0.f};
            #pragma unroll
            for (int h = 0; h < HH; ++h) {
                f32x4 wa = *reinterpret_cast<const f32x4*>(&swr[h * 8]);
                f32x4 wb = *reinterpret_cast<const f32x4*>(&swr[h * 8 + 4]);
                xv[0] += (f32x2){wa[0], wa[1]} * vr[h];
                xv[1] += (f32x2){wa[2], wa[3]} * vr[h];
                xv[2] += (f32x2){wb[0], wb[1]} * vr[h];
                xv[3] += (f32x2){wb[2], wb[3]} * vr[h];
            }
            #pragma unroll
            for (int qp = 0; qp < 4; ++qp) {
                xv[qp][0] = fast_silu(xv[qp][0]);
                xv[qp][1] = fast_silu(xv[qp][1]);
            }
            #pragma unroll
            for (int h = 0; h < HH; ++h) {
                f32x4 wa = *reinterpret_cast<const f32x4*>(&swr[h * 8]);
                f32x4 wb = *reinterpret_cast<const f32x4*>(&swr[h * 8 + 4]);
                oacc[0][h] += (f32x2){wa[0], wa[1]} * xv[0];
                oacc[1][h] += (f32x2){wa[2], wa[3]} * xv[1];
                oacc[2][h] += (f32x2){wb[0], wb[1]} * xv[2];
                oacc[3][h] += (f32x2){wb[2], wb[3]} * xv[3];
            }
        }
    }

    // ---- cross-wave reduce + bf16 partial store (2 q per pass) ----
    float* red = sw;
    short* outp = ATTp + ((size_t)ksp * NROWS + bq0) * EE;
    for (int qq = 0; qq < 4; ++qq) {
        __syncthreads();
        #pragma unroll
        for (int q2 = 0; q2 < 2; ++q2)
            #pragma unroll
            for (int h = 0; h < HH; ++h)
                red[q2 * 2048 + wave * 512 + h * 64 + lane] = oacc[qq][h][q2];
        __syncthreads();
        #pragma unroll
        for (int i2 = 0; i2 < 4; ++i2) {
            int idx = i2 * 256 + tid;
            int q2 = idx >> 9, e = idx & 511;
            int base = q2 * 2048 + e;
            float s = red[base] + red[base + 512] + red[base + 1024] + red[base + 1536];
            outp[(size_t)(qq * 2 + q2) * EE + e] = to_bf16(s);
        }
    }
}

extern "C" void kernel_launch(void* const* d_in, const int* in_sizes, int n_in,
                              void* d_out, int out_size, void* d_ws, size_t ws_size,
                              hipStream_t stream) {
    const float* query = (const float*)d_in[0];
    const float* key   = (const float*)d_in[1];
    const float* value = (const float*)d_in[2];
    const float* Wq = (const float*)d_in[3];
    const float* biasq = (const float*)d_in[4];
    const float* Wk = (const float*)d_in[5];
    const float* biask = (const float*)d_in[6];
    const float* Wv = (const float*)d_in[7];
    const float* biasv = (const float*)d_in[8];
    const float* Wo = (const float*)d_in[9];
    const float* biaso = (const float*)d_in[10];
    float* out = (float*)d_out;

    char* wsb = (char*)d_ws;
    short* Qb  = (short*)(wsb);                    // 2 MB bf16
    short* Kb  = (short*)(wsb + (2u << 20));       // 2 MB bf16
    float* Vb  = (float*)(wsb + (4u << 20));       // 4 MB f32
    short* ATTp = (short*)(wsb + (8u << 20));      // 16 MB bf16 partials [8][2048][512]

    dim3 gQKV(NROWS / 64, EE / 64, 3);
    qkv_gemm<<<gQKV, 256, 0, stream>>>(query, key, value, Wq, Wk, Wv,
                                       biasq, biask, biasv, Qb, Kb, Vb);

    attn5<<<dim3(NROWS / QT * KSPLIT, 1, 1), dim3(256, 1, 1), 0, stream>>>(Qb, Kb, Vb, ATTp);

    gemmO<<<dim3(NROWS / 64, EE / 64, 1), 256, 0, stream>>>(ATTp, Wo, biaso, out);
}

// Round 6
// 324.222 us; speedup vs baseline: 2.9019x; 2.9019x over previous
//
#include <hip/hip_runtime.h>
#include <hip/hip_bf16.h>
#include <math.h>

#define BB 2
#define LL 1024
#define EE 512
#define HH 8
#define DD 64
#define NROWS (BB*LL)   // 2048
#define QT 8
#define KSPLIT 8
#define KRANGE (LL/KSPLIT)  // 128

typedef __attribute__((ext_vector_type(4))) float f32x4;
typedef __attribute__((ext_vector_type(2))) float f32x2;
typedef __attribute__((ext_vector_type(8))) short short8;

static __device__ __forceinline__ short to_bf16(float f) {
    __bf16 h = (__bf16)f;
    return __builtin_bit_cast(short, h);
}

static __device__ __forceinline__ float from_bf16(short s) {
    unsigned u = ((unsigned)(unsigned short)s) << 16;
    return __builtin_bit_cast(float, u);
}

static __device__ __forceinline__ float fast_silu(float x) {
    float e = __expf(-x);
    return x * __builtin_amdgcn_rcpf(1.f + e);
}

// -------- shared MFMA GEMM core: acc += X[64-tile] @ W[64-tile]^T (bf16) --------
__device__ __forceinline__ void gemm_core(const float* __restrict__ X,
                                          const float* __restrict__ W,
                                          short* As, short* Bs,
                                          int m0, int n0, f32x4 (&acc)[2][2])
{
    const int tid  = threadIdx.x;
    const int lane = tid & 63, wave = tid >> 6;
    const int wr = wave >> 1, wc = wave & 1;
    const int r = tid >> 2, cq = tid & 3;
    const float* ax = X + (size_t)(m0 + r) * EE + cq * 8;
    const float* bx = W + (size_t)(n0 + r) * EE + cq * 8;

    float a_reg[8], b_reg[8];
    #pragma unroll
    for (int j = 0; j < 8; ++j) { a_reg[j] = ax[j]; b_reg[j] = bx[j]; }

    short* apos = &As[r * 32 + ((cq ^ (r & 3)) * 8)];
    short* bpos = &Bs[r * 32 + ((cq ^ (r & 3)) * 8)];
    const int swz = ((lane >> 4) ^ (lane & 3)) * 8;

    for (int it = 0; it < 16; ++it) {
        short8 av, bv;
        #pragma unroll
        for (int j = 0; j < 8; ++j) { av[j] = to_bf16(a_reg[j]); bv[j] = to_bf16(b_reg[j]); }
        __syncthreads();
        *reinterpret_cast<short8*>(apos) = av;
        *reinterpret_cast<short8*>(bpos) = bv;
        __syncthreads();
        if (it < 15) {
            const float* axn = ax + (it + 1) * 32;
            const float* bxn = bx + (it + 1) * 32;
            #pragma unroll
            for (int j = 0; j < 8; ++j) { a_reg[j] = axn[j]; b_reg[j] = bxn[j]; }
        }
        short8 af[2], bf[2];
        #pragma unroll
        for (int mi = 0; mi < 2; ++mi) {
            int row = wr * 32 + mi * 16 + (lane & 15);
            af[mi] = *reinterpret_cast<short8*>(&As[row * 32 + swz]);
        }
        #pragma unroll
        for (int ni = 0; ni < 2; ++ni) {
            int row = wc * 32 + ni * 16 + (lane & 15);
            bf[ni] = *reinterpret_cast<short8*>(&Bs[row * 32 + swz]);
        }
        #pragma unroll
        for (int mi = 0; mi < 2; ++mi)
            #pragma unroll
            for (int ni = 0; ni < 2; ++ni)
                acc[mi][ni] = __builtin_amdgcn_mfma_f32_16x16x32_bf16(af[mi], bf[ni], acc[mi][ni], 0, 0, 0);
    }
}

// -------- fused Q/K/V projections; z=0:Q(bf16) z=1:K(bf16) z=2:V(f32) --------
__global__ __launch_bounds__(256) void qkv_gemm(const float* __restrict__ q_in,
                                                const float* __restrict__ k_in,
                                                const float* __restrict__ v_in,
                                                const float* __restrict__ Wq,
                                                const float* __restrict__ Wk,
                                                const float* __restrict__ Wv,
                                                const float* __restrict__ bq,
                                                const float* __restrict__ bk,
                                                const float* __restrict__ bv,
                                                short* __restrict__ Qo,
                                                short* __restrict__ Ko,
                                                float* __restrict__ Vo)
{
    __shared__ short As[64 * 32];
    __shared__ short Bs[64 * 32];
    const int z = blockIdx.z;
    const float* X = (z == 0) ? q_in : (z == 1) ? k_in : v_in;
    const float* W = (z == 0) ? Wq : (z == 1) ? Wk : Wv;
    const float* bias = (z == 0) ? bq : (z == 1) ? bk : bv;

    const int m0 = blockIdx.x * 64, n0 = blockIdx.y * 64;
    f32x4 acc[2][2];
    #pragma unroll
    for (int mi = 0; mi < 2; ++mi)
        #pragma unroll
        for (int ni = 0; ni < 2; ++ni) acc[mi][ni] = (f32x4){0.f,0.f,0.f,0.f};

    gemm_core(X, W, As, Bs, m0, n0, acc);

    const int tid = threadIdx.x, lane = tid & 63, wave = tid >> 6;
    const int wr = wave >> 1, wc = wave & 1;
    const int col_l = lane & 15, rowg = (lane >> 4) * 4;
    #pragma unroll
    for (int mi = 0; mi < 2; ++mi)
        #pragma unroll
        for (int ni = 0; ni < 2; ++ni) {
            int colg = n0 + wc * 32 + ni * 16 + col_l;
            float bn = bias[colg];
            #pragma unroll
            for (int rr = 0; rr < 4; ++rr) {
                int mg = m0 + wr * 32 + mi * 16 + rowg + rr;
                float v = acc[mi][ni][rr] + bn;
                if (z == 2) Vo[(size_t)mg * EE + colg] = v;
                else {
                    short* ob = z ? Ko : Qo;
                    ob[(size_t)mg * EE + colg] = to_bf16(v);
                }
            }
        }
}

// -------- output GEMM: X = sum of 8 bf16 partial arrays --------
__global__ __launch_bounds__(256) void gemmO(const short* __restrict__ P,   // [KSPLIT][2048][512] bf16
                                             const float* __restrict__ W,
                                             const float* __restrict__ bias,
                                             float* __restrict__ out)
{
    __shared__ short As[64 * 32];
    __shared__ short Bs[64 * 32];
    const int tid  = threadIdx.x;
    const int lane = tid & 63, wave = tid >> 6;
    const int wr = wave >> 1, wc = wave & 1;
    const int m0 = blockIdx.x * 64, n0 = blockIdx.y * 64;
    const int r = tid >> 2, cq = tid & 3;
    const size_t PSZ = (size_t)NROWS * EE;

    size_t xoff = (size_t)(m0 + r) * EE + cq * 8;
    const float* bx = W + (size_t)(n0 + r) * EE + cq * 8;

    float a_reg[8], b_reg[8];
    #pragma unroll
    for (int j = 0; j < 8; ++j) { a_reg[j] = 0.f; b_reg[j] = bx[j]; }
    #pragma unroll
    for (int p = 0; p < KSPLIT; ++p) {
        short8 v = *reinterpret_cast<const short8*>(&P[p * PSZ + xoff]);
        #pragma unroll
        for (int j = 0; j < 8; ++j) a_reg[j] += from_bf16(v[j]);
    }

    f32x4 acc[2][2];
    #pragma unroll
    for (int mi = 0; mi < 2; ++mi)
        #pragma unroll
        for (int ni = 0; ni < 2; ++ni) acc[mi][ni] = (f32x4){0.f,0.f,0.f,0.f};

    short* apos = &As[r * 32 + ((cq ^ (r & 3)) * 8)];
    short* bpos = &Bs[r * 32 + ((cq ^ (r & 3)) * 8)];
    const int swz = ((lane >> 4) ^ (lane & 3)) * 8;

    for (int it = 0; it < 16; ++it) {
        short8 av, bv;
        #pragma unroll
        for (int j = 0; j < 8; ++j) { av[j] = to_bf16(a_reg[j]); bv[j] = to_bf16(b_reg[j]); }
        __syncthreads();
        *reinterpret_cast<short8*>(apos) = av;
        *reinterpret_cast<short8*>(bpos) = bv;
        __syncthreads();
        if (it < 15) {
            size_t xo = xoff + (it + 1) * 32;
            const float* bxn = bx + (it + 1) * 32;
            #pragma unroll
            for (int j = 0; j < 8; ++j) { a_reg[j] = 0.f; b_reg[j] = bxn[j]; }
            #pragma unroll
            for (int p = 0; p < KSPLIT; ++p) {
                short8 v = *reinterpret_cast<const short8*>(&P[p * PSZ + xo]);
                #pragma unroll
                for (int j = 0; j < 8; ++j) a_reg[j] += from_bf16(v[j]);
            }
        }
        short8 af[2], bf[2];
        #pragma unroll
        for (int mi = 0; mi < 2; ++mi) {
            int row = wr * 32 + mi * 16 + (lane & 15);
            af[mi] = *reinterpret_cast<short8*>(&As[row * 32 + swz]);
        }
        #pragma unroll
        for (int ni = 0; ni < 2; ++ni) {
            int row = wc * 32 + ni * 16 + (lane & 15);
            bf[ni] = *reinterpret_cast<short8*>(&Bs[row * 32 + swz]);
        }
        #pragma unroll
        for (int mi = 0; mi < 2; ++mi)
            #pragma unroll
            for (int ni = 0; ni < 2; ++ni)
                acc[mi][ni] = __builtin_amdgcn_mfma_f32_16x16x32_bf16(af[mi], bf[ni], acc[mi][ni], 0, 0, 0);
    }

    const int col_l = lane & 15, rowg = (lane >> 4) * 4;
    #pragma unroll
    for (int mi = 0; mi < 2; ++mi)
        #pragma unroll
        for (int ni = 0; ni < 2; ++ni) {
            int colg = n0 + wc * 32 + ni * 16 + col_l;
            float bn = bias[colg];
            #pragma unroll
            for (int rr = 0; rr < 4; ++rr) {
                int mg = m0 + wr * 32 + mi * 16 + rowg + rr;
                out[(size_t)mg * EE + colg] = acc[mi][ni][rr] + bn;
            }
        }
}

// -------- fused attention --------
// Qb,Kb: bf16 [B*L][E]; V: f32 [B*L][E]; ATTp: bf16 [KSPLIT][B*L][E] partials.
// sw layout: [k(64)][h*8 + q], row stride 68 floats.
// NOTE: __launch_bounds__(256,4) — (256,6) forced VGPR=40 and spilled oacc to
// scratch (R5: 4.1 GB HBM traffic, 833 µs). VGPR=64 codegen proven in R3.
__global__ __launch_bounds__(256, 4) void attn6(const short* __restrict__ Qb,
                                                const short* __restrict__ Kb,
                                                const float* __restrict__ V,
                                                short* __restrict__ ATTp)
{
    __shared__ float sw[64 * 68];     // 17.4 KB (only LDS)

    const int tid = threadIdx.x, lane = tid & 63, wave = tid >> 6;

    // XCD-aware decode over 2048 blocks
    const int fid = blockIdx.x;                    // 0..2047
    const int newid = (fid & 7) * 256 + (fid >> 3);
    const int b = newid >> 10;
    const int ksp = (newid >> 7) & 7;
    const int qpos = newid & 127;
    const int bq0 = b * LL + qpos * QT;
    const int k0base = ksp * KRANGE;

    f32x2 oacc[4][HH];
    #pragma unroll
    for (int qp = 0; qp < 4; ++qp)
        #pragma unroll
        for (int h = 0; h < HH; ++h) oacc[qp][h] = (f32x2){0.f, 0.f};

    const int qr = lane & 7;
    const int kg4 = lane >> 4;

    for (int t = 0; t < KRANGE / 64; ++t) {
        const int k0 = k0base + t * 64;
        __syncthreads();   // sw free (prev phase 3 done)

        // ---- phase 1: MFMA scores S^T[k][q] for heads {wave, wave+4} ----
        const short* kbase = Kb + ((size_t)(b * LL + k0) << 9);
        const short* qrow = Qb + ((size_t)(bq0 + qr) << 9);
        #pragma unroll
        for (int hh = 0; hh < 2; ++hh) {
            const int h = wave + hh * 4;
            short8 bfq[2];
            #pragma unroll
            for (int kc = 0; kc < 2; ++kc)
                bfq[kc] = *reinterpret_cast<const short8*>(qrow + ((h * 8 + kc * 4 + kg4) << 3));
            f32x4 acc[4];
            #pragma unroll
            for (int m = 0; m < 4; ++m) acc[m] = (f32x4){0.f,0.f,0.f,0.f};
            #pragma unroll
            for (int m = 0; m < 4; ++m) {
                const short* arow = kbase + ((size_t)(m * 16 + (lane & 15)) << 9) + (h << 6) + (kg4 << 3);
                short8 af0 = *reinterpret_cast<const short8*>(arow);
                short8 af1 = *reinterpret_cast<const short8*>(arow + 32);
                acc[m] = __builtin_amdgcn_mfma_f32_16x16x32_bf16(af0, bfq[0], acc[m], 0, 0, 0);
                acc[m] = __builtin_amdgcn_mfma_f32_16x16x32_bf16(af1, bfq[1], acc[m], 0, 0, 0);
            }
            if ((lane & 15) < 8) {
                int q = lane & 15;
                #pragma unroll
                for (int m = 0; m < 4; ++m)
                    #pragma unroll
                    for (int r = 0; r < 4; ++r) {
                        int k = m * 16 + kg4 * 4 + r;
                        sw[k * 68 + h * 8 + q] = acc[m][r] * 0.125f;
                    }
            }
        }
        __syncthreads();

        // ---- phase 2: RMS over heads, normalize in place ----
        #pragma unroll
        for (int rep = 0; rep < 2; ++rep) {
            int idx = rep * 256 + tid;
            int k = idx >> 3, q = idx & 7;
            float* sp = &sw[k * 68 + q];
            float s[HH], ss = 0.f;
            #pragma unroll
            for (int h = 0; h < HH; ++h) { s[h] = sp[h * 8]; ss += s[h] * s[h]; }
            float inv = __builtin_amdgcn_rsqf(ss * 0.125f + 1e-8f);
            #pragma unroll
            for (int h = 0; h < HH; ++h) sp[h * 8] = s[h] * inv;
        }
        __syncthreads();

        // ---- phase 3: rolled loop; lane = d, k = j*4+wave ----
        for (int j = 0; j < 16; ++j) {
            int kl = j * 4 + wave;
            const float* vp = V + ((size_t)(b * LL + k0 + kl) << 9) + lane;
            float vr[HH];
            #pragma unroll
            for (int h = 0; h < HH; ++h) vr[h] = vp[h * DD];
            const float* swr = &sw[kl * 68];
            f32x2 xv[4];
            #pragma unroll
            for (int qp = 0; qp < 4; ++qp) xv[qp] = (f32x2){0.f, 0.f};
            #pragma unroll
            for (int h = 0; h < HH; ++h) {
                f32x4 wa = *reinterpret_cast<const f32x4*>(&swr[h * 8]);
                f32x4 wb = *reinterpret_cast<const f32x4*>(&swr[h * 8 + 4]);
                xv[0] += (f32x2){wa[0], wa[1]} * vr[h];
                xv[1] += (f32x2){wa[2], wa[3]} * vr[h];
                xv[2] += (f32x2){wb[0], wb[1]} * vr[h];
                xv[3] += (f32x2){wb[2], wb[3]} * vr[h];
            }
            #pragma unroll
            for (int qp = 0; qp < 4; ++qp) {
                xv[qp][0] = fast_silu(xv[qp][0]);
                xv[qp][1] = fast_silu(xv[qp][1]);
            }
            #pragma unroll
            for (int h = 0; h < HH; ++h) {
                f32x4 wa = *reinterpret_cast<const f32x4*>(&swr[h * 8]);
                f32x4 wb = *reinterpret_cast<const f32x4*>(&swr[h * 8 + 4]);
                oacc[0][h] += (f32x2){wa[0], wa[1]} * xv[0];
                oacc[1][h] += (f32x2){wa[2], wa[3]} * xv[1];
                oacc[2][h] += (f32x2){wb[0], wb[1]} * xv[2];
                oacc[3][h] += (f32x2){wb[2], wb[3]} * xv[3];
            }
        }
    }

    // ---- cross-wave reduce + bf16 partial store (2 q per pass) ----
    float* red = sw;
    short* outp = ATTp + ((size_t)ksp * NROWS + bq0) * EE;
    for (int qq = 0; qq < 4; ++qq) {
        __syncthreads();
        #pragma unroll
        for (int q2 = 0; q2 < 2; ++q2)
            #pragma unroll
            for (int h = 0; h < HH; ++h)
                red[q2 * 2048 + wave * 512 + h * 64 + lane] = oacc[qq][h][q2];
        __syncthreads();
        #pragma unroll
        for (int i2 = 0; i2 < 4; ++i2) {
            int idx = i2 * 256 + tid;
            int q2 = idx >> 9, e = idx & 511;
            int base = q2 * 2048 + e;
            float s = red[base] + red[base + 512] + red[base + 1024] + red[base + 1536];
            outp[(size_t)(qq * 2 + q2) * EE + e] = to_bf16(s);
        }
    }
}

extern "C" void kernel_launch(void* const* d_in, const int* in_sizes, int n_in,
                              void* d_out, int out_size, void* d_ws, size_t ws_size,
                              hipStream_t stream) {
    const float* query = (const float*)d_in[0];
    const float* key   = (const float*)d_in[1];
    const float* value = (const float*)d_in[2];
    const float* Wq = (const float*)d_in[3];
    const float* biasq = (const float*)d_in[4];
    const float* Wk = (const float*)d_in[5];
    const float* biask = (const float*)d_in[6];
    const float* Wv = (const float*)d_in[7];
    const float* biasv = (const float*)d_in[8];
    const float* Wo = (const float*)d_in[9];
    const float* biaso = (const float*)d_in[10];
    float* out = (float*)d_out;

    char* wsb = (char*)d_ws;
    short* Qb  = (short*)(wsb);                    // 2 MB bf16
    short* Kb  = (short*)(wsb + (2u << 20));       // 2 MB bf16
    float* Vb  = (float*)(wsb + (4u << 20));       // 4 MB f32
    short* ATTp = (short*)(wsb + (8u << 20));      // 16 MB bf16 partials [8][2048][512]

    dim3 gQKV(NROWS / 64, EE / 64, 3);
    qkv_gemm<<<gQKV, 256, 0, stream>>>(query, key, value, Wq, Wk, Wv,
                                       biasq, biask, biasv, Qb, Kb, Vb);

    attn6<<<dim3(NROWS / QT * KSPLIT, 1, 1), dim3(256, 1, 1), 0, stream>>>(Qb, Kb, Vb, ATTp);

    gemmO<<<dim3(NROWS / 64, EE / 64, 1), 256, 0, stream>>>(ATTp, Wo, biaso, out);
}

// Round 7
// 305.374 us; speedup vs baseline: 3.0810x; 1.0617x over previous
//
#include <hip/hip_runtime.h>
#include <hip/hip_bf16.h>
#include <math.h>

#define BB 2
#define LL 1024
#define EE 512
#define HH 8
#define DD 64
#define NROWS (BB*LL)   // 2048
#define QT 8
#define KSPLIT 4
#define KRANGE (LL/KSPLIT)  // 256

typedef __attribute__((ext_vector_type(4))) float f32x4;
typedef __attribute__((ext_vector_type(2))) float f32x2;
typedef __attribute__((ext_vector_type(8))) short short8;

static __device__ __forceinline__ short to_bf16(float f) {
    __bf16 h = (__bf16)f;
    return __builtin_bit_cast(short, h);
}

static __device__ __forceinline__ float from_bf16(short s) {
    unsigned u = ((unsigned)(unsigned short)s) << 16;
    return __builtin_bit_cast(float, u);
}

static __device__ __forceinline__ float fast_silu(float x) {
    float e = __expf(-x);
    return x * __builtin_amdgcn_rcpf(1.f + e);
}

// -------- shared MFMA GEMM core: acc += X[64-tile] @ W[64-tile]^T (bf16) --------
__device__ __forceinline__ void gemm_core(const float* __restrict__ X,
                                          const float* __restrict__ W,
                                          short* As, short* Bs,
                                          int m0, int n0, f32x4 (&acc)[2][2])
{
    const int tid  = threadIdx.x;
    const int lane = tid & 63, wave = tid >> 6;
    const int wr = wave >> 1, wc = wave & 1;
    const int r = tid >> 2, cq = tid & 3;
    const float* ax = X + (size_t)(m0 + r) * EE + cq * 8;
    const float* bx = W + (size_t)(n0 + r) * EE + cq * 8;

    float a_reg[8], b_reg[8];
    #pragma unroll
    for (int j = 0; j < 8; ++j) { a_reg[j] = ax[j]; b_reg[j] = bx[j]; }

    short* apos = &As[r * 32 + ((cq ^ (r & 3)) * 8)];
    short* bpos = &Bs[r * 32 + ((cq ^ (r & 3)) * 8)];
    const int swz = ((lane >> 4) ^ (lane & 3)) * 8;

    for (int it = 0; it < 16; ++it) {
        short8 av, bv;
        #pragma unroll
        for (int j = 0; j < 8; ++j) { av[j] = to_bf16(a_reg[j]); bv[j] = to_bf16(b_reg[j]); }
        __syncthreads();
        *reinterpret_cast<short8*>(apos) = av;
        *reinterpret_cast<short8*>(bpos) = bv;
        __syncthreads();
        if (it < 15) {
            const float* axn = ax + (it + 1) * 32;
            const float* bxn = bx + (it + 1) * 32;
            #pragma unroll
            for (int j = 0; j < 8; ++j) { a_reg[j] = axn[j]; b_reg[j] = bxn[j]; }
        }
        short8 af[2], bf[2];
        #pragma unroll
        for (int mi = 0; mi < 2; ++mi) {
            int row = wr * 32 + mi * 16 + (lane & 15);
            af[mi] = *reinterpret_cast<short8*>(&As[row * 32 + swz]);
        }
        #pragma unroll
        for (int ni = 0; ni < 2; ++ni) {
            int row = wc * 32 + ni * 16 + (lane & 15);
            bf[ni] = *reinterpret_cast<short8*>(&Bs[row * 32 + swz]);
        }
        #pragma unroll
        for (int mi = 0; mi < 2; ++mi)
            #pragma unroll
            for (int ni = 0; ni < 2; ++ni)
                acc[mi][ni] = __builtin_amdgcn_mfma_f32_16x16x32_bf16(af[mi], bf[ni], acc[mi][ni], 0, 0, 0);
    }
}

// -------- fused Q/K/V projections; z=0:Q(bf16) z=1:K(bf16) z=2:V(packed bf16) --------
// V packed layout: row mg, element (d*8 + h) where colg = h*64+d.
__global__ __launch_bounds__(256) void qkv_gemm(const float* __restrict__ q_in,
                                                const float* __restrict__ k_in,
                                                const float* __restrict__ v_in,
                                                const float* __restrict__ Wq,
                                                const float* __restrict__ Wk,
                                                const float* __restrict__ Wv,
                                                const float* __restrict__ bq,
                                                const float* __restrict__ bk,
                                                const float* __restrict__ bv,
                                                short* __restrict__ Qo,
                                                short* __restrict__ Ko,
                                                short* __restrict__ Vo)
{
    __shared__ short As[64 * 32];
    __shared__ short Bs[64 * 32];
    const int z = blockIdx.z;
    const float* X = (z == 0) ? q_in : (z == 1) ? k_in : v_in;
    const float* W = (z == 0) ? Wq : (z == 1) ? Wk : Wv;
    const float* bias = (z == 0) ? bq : (z == 1) ? bk : bv;

    const int m0 = blockIdx.x * 64, n0 = blockIdx.y * 64;
    f32x4 acc[2][2];
    #pragma unroll
    for (int mi = 0; mi < 2; ++mi)
        #pragma unroll
        for (int ni = 0; ni < 2; ++ni) acc[mi][ni] = (f32x4){0.f,0.f,0.f,0.f};

    gemm_core(X, W, As, Bs, m0, n0, acc);

    const int tid = threadIdx.x, lane = tid & 63, wave = tid >> 6;
    const int wr = wave >> 1, wc = wave & 1;
    const int col_l = lane & 15, rowg = (lane >> 4) * 4;
    #pragma unroll
    for (int mi = 0; mi < 2; ++mi)
        #pragma unroll
        for (int ni = 0; ni < 2; ++ni) {
            int colg = n0 + wc * 32 + ni * 16 + col_l;
            float bn = bias[colg];
            #pragma unroll
            for (int rr = 0; rr < 4; ++rr) {
                int mg = m0 + wr * 32 + mi * 16 + rowg + rr;
                float v = acc[mi][ni][rr] + bn;
                if (z == 2) Vo[(size_t)mg * EE + ((colg & 63) << 3) + (colg >> 6)] = to_bf16(v);
                else {
                    short* ob = z ? Ko : Qo;
                    ob[(size_t)mg * EE + colg] = to_bf16(v);
                }
            }
        }
}

// -------- plain f32-out GEMM (final projection) --------
__global__ __launch_bounds__(256) void gemm_f32(const float* __restrict__ X,
                                                const float* __restrict__ W,
                                                const float* __restrict__ bias,
                                                float* __restrict__ out)
{
    __shared__ short As[64 * 32];
    __shared__ short Bs[64 * 32];
    const int m0 = blockIdx.x * 64, n0 = blockIdx.y * 64;
    f32x4 acc[2][2];
    #pragma unroll
    for (int mi = 0; mi < 2; ++mi)
        #pragma unroll
        for (int ni = 0; ni < 2; ++ni) acc[mi][ni] = (f32x4){0.f,0.f,0.f,0.f};

    gemm_core(X, W, As, Bs, m0, n0, acc);

    const int tid = threadIdx.x, lane = tid & 63, wave = tid >> 6;
    const int wr = wave >> 1, wc = wave & 1;
    const int col_l = lane & 15, rowg = (lane >> 4) * 4;
    #pragma unroll
    for (int mi = 0; mi < 2; ++mi)
        #pragma unroll
        for (int ni = 0; ni < 2; ++ni) {
            int colg = n0 + wc * 32 + ni * 16 + col_l;
            float bn = bias[colg];
            #pragma unroll
            for (int rr = 0; rr < 4; ++rr) {
                int mg = m0 + wr * 32 + mi * 16 + rowg + rr;
                out[(size_t)mg * EE + colg] = acc[mi][ni][rr] + bn;
            }
        }
}

// -------- fused attention (R3-attn3 structure + fast_silu + packed-bf16 V) --------
// Qb,Kb: bf16 [B*L][E]; Vp: packed bf16 [B*L][d*8+h]; ATT: f32 via atomicAdd.
// sw layout: [k(64)][h*8 + q], row stride 68 floats.
__global__ __launch_bounds__(256, 4) void attn7(const short* __restrict__ Qb,
                                                const short* __restrict__ Kb,
                                                const short* __restrict__ Vp,
                                                float* __restrict__ ATT)
{
    __shared__ short Qs[QT * EE];     // 8 KB, XOR-swizzled 8-elem chunks
    __shared__ float sw[64 * 68];     // 17.4 KB

    const int tid = threadIdx.x, lane = tid & 63, wave = tid >> 6;

    // XCD-aware decode: each XCD chunk owns one (b, k-quarter)
    const int fid = blockIdx.x;                    // 0..1023
    const int newid = (fid & 7) * 128 + (fid >> 3);
    const int b = newid >> 9;
    const int ksp = (newid >> 7) & 3;
    const int qpos = newid & 127;
    const int bq0 = b * LL + qpos * QT;
    const int k0base = ksp * KRANGE;

    // stage Q tile (bf16), XOR swizzle chunk c -> c^q
    for (int i = tid; i < QT * 64; i += 256) {
        int q = i >> 6, c = i & 63;
        short8 v = *reinterpret_cast<const short8*>(Qb + ((size_t)(bq0 + q) << 9) + c * 8);
        *reinterpret_cast<short8*>(&Qs[(q << 9) + ((c ^ q) << 3)]) = v;
    }

    f32x2 oacc[4][HH];
    #pragma unroll
    for (int qp = 0; qp < 4; ++qp)
        #pragma unroll
        for (int h = 0; h < HH; ++h) oacc[qp][h] = (f32x2){0.f, 0.f};

    const int qr = lane & 7;
    const int kg4 = lane >> 4;

    for (int t = 0; t < KRANGE / 64; ++t) {
        const int k0 = k0base + t * 64;
        __syncthreads();   // sw free (prev phase 3 done); Qs ready (t==0)

        // ---- phase 1: MFMA scores S^T[k][q] for heads {wave, wave+4} ----
        const short* kbase = Kb + ((size_t)(b * LL + k0) << 9);
        #pragma unroll
        for (int hh = 0; hh < 2; ++hh) {
            const int h = wave + hh * 4;
            short8 bfq[2];
            #pragma unroll
            for (int kc = 0; kc < 2; ++kc) {
                int c = h * 8 + kc * 4 + kg4;
                bfq[kc] = *reinterpret_cast<const short8*>(&Qs[(qr << 9) + ((c ^ qr) << 3)]);
            }
            f32x4 acc[4];
            #pragma unroll
            for (int m = 0; m < 4; ++m) acc[m] = (f32x4){0.f,0.f,0.f,0.f};
            #pragma unroll
            for (int m = 0; m < 4; ++m) {
                const short* arow = kbase + ((size_t)(m * 16 + (lane & 15)) << 9) + (h << 6) + (kg4 << 3);
                short8 af0 = *reinterpret_cast<const short8*>(arow);
                short8 af1 = *reinterpret_cast<const short8*>(arow + 32);
                acc[m] = __builtin_amdgcn_mfma_f32_16x16x32_bf16(af0, bfq[0], acc[m], 0, 0, 0);
                acc[m] = __builtin_amdgcn_mfma_f32_16x16x32_bf16(af1, bfq[1], acc[m], 0, 0, 0);
            }
            if ((lane & 15) < 8) {
                int q = lane & 15;
                #pragma unroll
                for (int m = 0; m < 4; ++m)
                    #pragma unroll
                    for (int r = 0; r < 4; ++r) {
                        int k = m * 16 + kg4 * 4 + r;
                        sw[k * 68 + h * 8 + q] = acc[m][r] * 0.125f;
                    }
            }
        }
        __syncthreads();

        // ---- phase 2: RMS over heads, normalize in place ----
        #pragma unroll
        for (int rep = 0; rep < 2; ++rep) {
            int idx = rep * 256 + tid;
            int k = idx >> 3, q = idx & 7;
            float* sp = &sw[k * 68 + q];
            float s[HH], ss = 0.f;
            #pragma unroll
            for (int h = 0; h < HH; ++h) { s[h] = sp[h * 8]; ss += s[h] * s[h]; }
            float inv = __builtin_amdgcn_rsqf(ss * 0.125f + 1e-8f);
            #pragma unroll
            for (int h = 0; h < HH; ++h) sp[h * 8] = s[h] * inv;
        }
        __syncthreads();

        // ---- phase 3: rolled loop; lane = d; one dwordx4 V load per (j) ----
        for (int j = 0; j < 16; ++j) {
            int kl = j * 4 + wave;
            short8 vv = *reinterpret_cast<const short8*>(
                Vp + ((size_t)(b * LL + k0 + kl) << 9) + (lane << 3));
            float vr[HH];
            #pragma unroll
            for (int h = 0; h < HH; ++h) vr[h] = from_bf16(vv[h]);
            const float* swr = &sw[kl * 68];
            f32x2 xv[4];
            #pragma unroll
            for (int qp = 0; qp < 4; ++qp) xv[qp] = (f32x2){0.f, 0.f};
            #pragma unroll
            for (int h = 0; h < HH; ++h) {
                f32x4 wa = *reinterpret_cast<const f32x4*>(&swr[h * 8]);
                f32x4 wb = *reinterpret_cast<const f32x4*>(&swr[h * 8 + 4]);
                xv[0] += (f32x2){wa[0], wa[1]} * vr[h];
                xv[1] += (f32x2){wa[2], wa[3]} * vr[h];
                xv[2] += (f32x2){wb[0], wb[1]} * vr[h];
                xv[3] += (f32x2){wb[2], wb[3]} * vr[h];
            }
            #pragma unroll
            for (int qp = 0; qp < 4; ++qp) {
                xv[qp][0] = fast_silu(xv[qp][0]);
                xv[qp][1] = fast_silu(xv[qp][1]);
            }
            #pragma unroll
            for (int h = 0; h < HH; ++h) {
                f32x4 wa = *reinterpret_cast<const f32x4*>(&swr[h * 8]);
                f32x4 wb = *reinterpret_cast<const f32x4*>(&swr[h * 8 + 4]);
                oacc[0][h] += (f32x2){wa[0], wa[1]} * xv[0];
                oacc[1][h] += (f32x2){wa[2], wa[3]} * xv[1];
                oacc[2][h] += (f32x2){wb[0], wb[1]} * xv[2];
                oacc[3][h] += (f32x2){wb[2], wb[3]} * xv[3];
            }
        }
    }

    // ---- cross-wave reduce + global accumulate (fully unrolled: static oacc idx) ----
    float* red = sw;
    #pragma unroll
    for (int q = 0; q < QT; ++q) {
        __syncthreads();
        #pragma unroll
        for (int h = 0; h < HH; ++h)
            red[(wave * HH + h) * 64 + lane] = oacc[q >> 1][h][q & 1];
        __syncthreads();
        #pragma unroll
        for (int i2 = 0; i2 < 2; ++i2) {
            int e = tid + i2 * 256;
            float sum = red[e] + red[e + 512] + red[e + 1024] + red[e + 1536];
            atomicAdd(&ATT[(size_t)(bq0 + q) * EE + e], sum);
        }
    }
}

extern "C" void kernel_launch(void* const* d_in, const int* in_sizes, int n_in,
                              void* d_out, int out_size, void* d_ws, size_t ws_size,
                              hipStream_t stream) {
    const float* query = (const float*)d_in[0];
    const float* key   = (const float*)d_in[1];
    const float* value = (const float*)d_in[2];
    const float* Wq = (const float*)d_in[3];
    const float* biasq = (const float*)d_in[4];
    const float* Wk = (const float*)d_in[5];
    const float* biask = (const float*)d_in[6];
    const float* Wv = (const float*)d_in[7];
    const float* biasv = (const float*)d_in[8];
    const float* Wo = (const float*)d_in[9];
    const float* biaso = (const float*)d_in[10];
    float* out = (float*)d_out;

    char* wsb = (char*)d_ws;
    short* Qb  = (short*)(wsb);                    // 2 MB bf16
    short* Kb  = (short*)(wsb + (2u << 20));       // 2 MB bf16
    short* Vb  = (short*)(wsb + (4u << 20));       // 2 MB packed bf16
    float* ATT = (float*)(wsb + (6u << 20));       // 4 MB f32

    hipMemsetAsync(ATT, 0, (size_t)NROWS * EE * sizeof(float), stream);

    dim3 gQKV(NROWS / 64, EE / 64, 3);
    qkv_gemm<<<gQKV, 256, 0, stream>>>(query, key, value, Wq, Wk, Wv,
                                       biasq, biask, biasv, Qb, Kb, Vb);

    attn7<<<dim3(NROWS / QT * KSPLIT, 1, 1), dim3(256, 1, 1), 0, stream>>>(Qb, Kb, Vb, ATT);

    gemm_f32<<<dim3(NROWS / 64, EE / 64, 1), 256, 0, stream>>>(ATT, Wo, biaso, out);
}